// Round 1
// baseline (192.620 us; speedup 1.0000x reference)
//
#include <hip/hip_runtime.h>
#include <hip/hip_bf16.h>

#define B 8
#define N 1024
#define E 10

// ---------------------------------------------------------------------------
// K1: column sums of weights: ppos[b,it,j] = sum_{i in tile} max(w[b,i,j],0)
//     pneg likewise for max(-w,0). Grid: 8 b x 32 row-tiles = 256 blocks.
//     Thread owns 4 consecutive columns (float4) -> fully coalesced 16B/lane.
// ---------------------------------------------------------------------------
__global__ __launch_bounds__(256) void k_colsum(const float* __restrict__ W,
                                                float* __restrict__ ppos,
                                                float* __restrict__ pneg) {
    int bi = blockIdx.x;
    int b  = bi >> 5;          // 0..7
    int it = bi & 31;          // 0..31, 32 rows each
    int j4 = threadIdx.x;      // 0..255 float4 column groups
    const float* wp = W + ((size_t)b * N + (size_t)it * 32) * N + (size_t)j4 * 4;
    float4 p = {0.f, 0.f, 0.f, 0.f};
    float4 q = {0.f, 0.f, 0.f, 0.f};
#pragma unroll 4
    for (int i = 0; i < 32; ++i) {
        float4 w = *(const float4*)(wp + (size_t)i * N);
        p.x += fmaxf(w.x, 0.f); q.x += fmaxf(-w.x, 0.f);
        p.y += fmaxf(w.y, 0.f); q.y += fmaxf(-w.y, 0.f);
        p.z += fmaxf(w.z, 0.f); q.z += fmaxf(-w.z, 0.f);
        p.w += fmaxf(w.w, 0.f); q.w += fmaxf(-w.w, 0.f);
    }
    *(float4*)(ppos + (size_t)(b * 32 + it) * N + (size_t)j4 * 4) = p;
    *(float4*)(pneg + (size_t)(b * 32 + it) * N + (size_t)j4 * 4) = q;
}

// ---------------------------------------------------------------------------
// K2: reduce partials, compute base[b,j,f] and emb0 = relu(base).
//     relu(w*c) summed over rows == c>0 ? c*spos : (-c)*sneg  (exact).
//     base[f] = feat*w_sel[f] + sum_e w_nbw[f,e]*s[e]
// ---------------------------------------------------------------------------
__global__ __launch_bounds__(256) void k_base(const float* __restrict__ ppos,
                                              const float* __restrict__ pneg,
                                              const float* __restrict__ features,
                                              const float* __restrict__ w_sel,
                                              const float* __restrict__ w_nbw,
                                              const float* __restrict__ w_ew,
                                              float* __restrict__ base,
                                              float* __restrict__ emb0) {
    int g = blockIdx.x * 256 + threadIdx.x;  // 0..8191 = b*1024 + j
    int b = g >> 10;
    int j = g & 1023;
    float sp = 0.f, sn = 0.f;
#pragma unroll 8
    for (int it = 0; it < 32; ++it) {
        sp += ppos[(size_t)(b * 32 + it) * N + j];
        sn += pneg[(size_t)(b * 32 + it) * N + j];
    }
    float s[E];
#pragma unroll
    for (int e = 0; e < E; ++e) {
        float c = w_ew[e];
        s[e] = (c > 0.f) ? c * sp : (-c) * sn;
    }
    float feat = features[g];
    float* bp = base + (size_t)g * E;
    float* ep = emb0 + (size_t)g * E;
#pragma unroll
    for (int f = 0; f < E; ++f) {
        float acc = feat * w_sel[f];
#pragma unroll
        for (int e = 0; e < E; ++e) acc += w_nbw[f * E + e] * s[e];
        bp[f] = acc;
        ep[f] = fmaxf(acc, 0.f);
    }
}

// ---------------------------------------------------------------------------
// K3: one embedding iteration:
//     v[i,e] = sum_j A[b,i,j]*ein[b,j,e];  eout = relu(base + v @ Wp^T)
//     Grid: 8 b x 32 row-tiles(32 rows) = 256 blocks x 256 threads.
//     A-tile transposed into LDS [128][33] (pad -> conflict-free),
//     lanes over 32 rows, 8 j-streams (4 waves x 2 half-waves).
// ---------------------------------------------------------------------------
#define TR 32
#define JC 128
__global__ __launch_bounds__(256) void k_iter(const float* __restrict__ A,
                                              const float* __restrict__ ein,
                                              const float* __restrict__ base,
                                              const float* __restrict__ Wp,
                                              float* __restrict__ eout) {
    __shared__ float At[JC][TR + 1];       // 128 x 33 = 16.9 KB
    __shared__ float vred[8][TR][E];       // 10.2 KB
    __shared__ float vsum[TR][E];          // 1.3 KB
    __shared__ float WpS[E * E];

    int bi   = blockIdx.x;
    int b    = bi >> 5;
    int tile = bi & 31;
    int i0   = tile * TR;
    int tid  = threadIdx.x;
    if (tid < E * E) WpS[tid] = Wp[tid];

    int wv   = tid >> 6;
    int lane = tid & 63;
    int r    = lane & 31;     // row within tile
    int h    = lane >> 5;     // half-wave
    int js   = wv * 2 + h;    // j-stream 0..7

    float acc[E];
#pragma unroll
    for (int e = 0; e < E; ++e) acc[e] = 0.f;

    const float* Ab = A + ((size_t)b * N + i0) * N;
    const float* Eb = ein + (size_t)b * N * E;

    for (int c = 0; c < N / JC; ++c) {
        // stage 32 rows x 128 cols, transposed, float4 global reads
#pragma unroll
        for (int k = 0; k < 4; ++k) {
            int idx = tid + k * 256;       // 0..1023 float4 units
            int rr  = idx >> 5;            // 0..31 row
            int jg  = idx & 31;            // 0..31 float4 col group
            float4 v = *(const float4*)(Ab + (size_t)rr * N + c * JC + jg * 4);
            At[jg * 4 + 0][rr] = v.x;
            At[jg * 4 + 1][rr] = v.y;
            At[jg * 4 + 2][rr] = v.z;
            At[jg * 4 + 3][rr] = v.w;
        }
        __syncthreads();
#pragma unroll
        for (int jj = 0; jj < 16; ++jj) {
            int j = js * 16 + jj;
            float a = At[j][r];
            const float* er = Eb + (size_t)(c * JC + j) * E;   // 40B rows, 8B aligned
            float2 e0 = *(const float2*)(er + 0);
            float2 e1 = *(const float2*)(er + 2);
            float2 e2 = *(const float2*)(er + 4);
            float2 e3 = *(const float2*)(er + 6);
            float2 e4 = *(const float2*)(er + 8);
            acc[0] += a * e0.x; acc[1] += a * e0.y;
            acc[2] += a * e1.x; acc[3] += a * e1.y;
            acc[4] += a * e2.x; acc[5] += a * e2.y;
            acc[6] += a * e3.x; acc[7] += a * e3.y;
            acc[8] += a * e4.x; acc[9] += a * e4.y;
        }
        __syncthreads();
    }

#pragma unroll
    for (int e = 0; e < E; ++e) vred[js][r][e] = acc[e];
    __syncthreads();

    // reduce the 8 j-streams
    for (int p = tid; p < TR * E; p += 256) {
        int rr = p / E, e = p % E;
        float s = 0.f;
#pragma unroll
        for (int ss = 0; ss < 8; ++ss) s += vred[ss][rr][e];
        vsum[rr][e] = s;
    }
    __syncthreads();

    // apply Wp, add base, relu, store (coalesced: p consecutive -> o consecutive)
    for (int p = tid; p < TR * E; p += 256) {
        int rr = p / E, f = p % E;
        float d = 0.f;
#pragma unroll
        for (int e = 0; e < E; ++e) d += vsum[rr][e] * WpS[f * E + e];
        size_t o = ((size_t)b * N + i0 + rr) * E + f;
        eout[o] = fmaxf(base[o] + d, 0.f);
    }
}

// ---------------------------------------------------------------------------
// K4: outputs. Fold w_q_reduc into the small matrices:
//     g_all[e] = sum_f w_reduc[f]   * w_all[f,e]
//     g_act[e] = sum_f w_reduc[E+f] * w_act[f,e]
//     q[b,n] = (sum_{n,e} emb*g_all) + dot(emb[b,n], g_act)
//     One block per batch.
// ---------------------------------------------------------------------------
__global__ __launch_bounds__(256) void k_out(const float* __restrict__ emb,
                                             const float* __restrict__ w_reduc,
                                             const float* __restrict__ w_all,
                                             const float* __restrict__ w_act,
                                             float* __restrict__ qv) {
    int b   = blockIdx.x;
    int tid = threadIdx.x;
    float g_all[E], g_act[E];
#pragma unroll
    for (int e = 0; e < E; ++e) {
        float sa = 0.f, sc = 0.f;
#pragma unroll
        for (int f = 0; f < E; ++f) {
            sa += w_reduc[f] * w_all[f * E + e];
            sc += w_reduc[E + f] * w_act[f * E + e];
        }
        g_all[e] = sa;
        g_act[e] = sc;
    }
    const float* Eb = emb + (size_t)b * N * E;
    float q2[4];
    float part = 0.f;
#pragma unroll
    for (int k = 0; k < 4; ++k) {
        int n = tid + k * 256;
        const float* er = Eb + (size_t)n * E;
        float dall = 0.f, dact = 0.f;
#pragma unroll
        for (int e = 0; e < E; ++e) {
            float v = er[e];
            dall += v * g_all[e];
            dact += v * g_act[e];
        }
        part += dall;
        q2[k] = dact;
    }
    // block reduction of part
#pragma unroll
    for (int off = 32; off >= 1; off >>= 1) part += __shfl_down(part, off, 64);
    __shared__ float wsum[4];
    if ((tid & 63) == 0) wsum[tid >> 6] = part;
    __syncthreads();
    float S = wsum[0] + wsum[1] + wsum[2] + wsum[3];
#pragma unroll
    for (int k = 0; k < 4; ++k) qv[b * N + tid + k * 256] = q2[k] + S;
}

extern "C" void kernel_launch(void* const* d_in, const int* in_sizes, int n_in,
                              void* d_out, int out_size, void* d_ws, size_t ws_size,
                              hipStream_t stream) {
    const float* features  = (const float*)d_in[0];
    const float* weights   = (const float*)d_in[1];
    const float* adjacency = (const float*)d_in[2];
    const float* w_sel     = (const float*)d_in[3];
    const float* w_pri     = (const float*)d_in[4];
    const float* w_nbw     = (const float*)d_in[5];
    const float* w_ew      = (const float*)d_in[6];
    const float* w_reduc   = (const float*)d_in[7];
    const float* w_all     = (const float*)d_in[8];
    const float* w_act     = (const float*)d_in[9];

    float* out     = (float*)d_out;
    float* qv      = out;              // B*N = 8192
    float* emb_out = out + B * N;      // B*N*E = 81920

    float* ws   = (float*)d_ws;
    float* ppos = ws;                          // B*32*N = 262144
    float* pneg = ppos + (size_t)B * 32 * N;   // 262144
    float* base = pneg + (size_t)B * 32 * N;   // B*N*E = 81920
    float* eA   = base + (size_t)B * N * E;    // 81920
    float* eB   = eA + (size_t)B * N * E;      // 81920

    k_colsum<<<256, 256, 0, stream>>>(weights, ppos, pneg);
    k_base<<<32, 256, 0, stream>>>(ppos, pneg, features, w_sel, w_nbw, w_ew, base, eA);
    // ref iter 1 (emb=0) == emb0 = relu(base); 4 remaining iterations:
    k_iter<<<256, 256, 0, stream>>>(adjacency, eA, base, w_pri, eB);
    k_iter<<<256, 256, 0, stream>>>(adjacency, eB, base, w_pri, eA);
    k_iter<<<256, 256, 0, stream>>>(adjacency, eA, base, w_pri, eB);
    k_iter<<<256, 256, 0, stream>>>(adjacency, eB, base, w_pri, emb_out);
    k_out<<<8, 256, 0, stream>>>(emb_out, w_reduc, w_all, w_act, qv);
}